// Round 2
// 828.543 us; speedup vs baseline: 1.0867x; 1.0867x over previous
//
#include <hip/hip_runtime.h>
#include <hip/hip_bf16.h>
#include <math.h>

typedef __hip_bfloat16 bf16;
typedef __bf16 bf16x8 __attribute__((ext_vector_type(8)));
typedef float f32x4 __attribute__((ext_vector_type(4)));

#define BDIM 16
#define SDIM 2048
#define FDIM 1024
#define BS (BDIM * SDIM)  // 32768

__device__ __forceinline__ float bf2f(bf16 x) { return __bfloat162float(x); }
__device__ __forceinline__ bf16 f2bf(float x) { return __float2bfloat16(x); }

// async global->LDS, 16B per lane. LDS dest is wave-uniform base + lane*16.
__device__ __forceinline__ void gload16(const void* g, void* l) {
  __builtin_amdgcn_global_load_lds(
      (const __attribute__((address_space(1))) unsigned int*)g,
      (__attribute__((address_space(3))) unsigned int*)l, 16, 0, 0);
}

// ---------------------------------------------------------------------------
// FAST GEMM (m97 structure): A [M,K] bf16 row-major staged via global_load_lds
// width=16; B [N,K] bf16 row-major (pre-transposed). K=1024, 128x128 tile,
// BK=32, 16x16x32 bf16 MFMA, 4 waves (2x2 of 64x64).
// MODE 0: val = relu(acc + bias[n]) -> OUTK: 0=bf16 out, 1=f32 out, 2=both
// MODE 1: logit[m] += sum_n tanh(acc[m,n] + t1[b,n]) * v[n]   (atomicAdd)
// ---------------------------------------------------------------------------
template <int MODE, int OUTK>
__global__ __launch_bounds__(256) void gemm_glds(
    const bf16* __restrict__ Ag, const bf16* __restrict__ Bg,
    const float* __restrict__ bias, bf16* __restrict__ outb,
    float* __restrict__ outf, const float* __restrict__ t1,
    const float* __restrict__ vvec, float* __restrict__ logit) {
  constexpr int BK = 32, K = 1024;
  __shared__ __align__(16) bf16 As[128 * BK];  // 8 KB, linear (glds requires)
  __shared__ __align__(16) bf16 Bs[128 * BK];  // 8 KB

  const int tid = threadIdx.x;
  const int lane = tid & 63;
  const int wave = tid >> 6;
  const int wm = (wave & 1) * 64;
  const int wn = (wave >> 1) * 64;
  const int tile_m = blockIdx.x * 128;
  const int tile_n = blockIdx.y * 128;
  const int ln = lane & 15;
  const int ko = (lane >> 4) * 8;

  f32x4 acc[4][4] = {};

  // glds addressing: wave w fills LDS bytes [w*1024, w*1024+1024) per call.
  // dest byte w*1024 + lane*16 == row (w*16 + lane/4) * 64B + (lane&3)*16B
  // of the linear [128][32] bf16 tile; chunk c covers rows [c*64, c*64+64).
  const int lrow = wave * 16 + (lane >> 2);
  const int lcolb = (lane & 3) * 16;
  const char* gA0 = (const char*)(Ag + (size_t)(tile_m + lrow) * K) + lcolb;
  const char* gA1 = (const char*)(Ag + (size_t)(tile_m + lrow + 64) * K) + lcolb;
  const char* gB0 = (const char*)(Bg + (size_t)(tile_n + lrow) * K) + lcolb;
  const char* gB1 = (const char*)(Bg + (size_t)(tile_n + lrow + 64) * K) + lcolb;
  char* lA0 = (char*)As + wave * 1024;
  char* lA1 = lA0 + 4096;
  char* lB0 = (char*)Bs + wave * 1024;
  char* lB1 = lB0 + 4096;

  for (int k0 = 0; k0 < K; k0 += BK) {
    __syncthreads();  // prev iteration's fragment reads complete before overwrite
    gload16(gA0, lA0);
    gload16(gA1, lA1);
    gload16(gB0, lB0);
    gload16(gB1, lB1);
    gA0 += 64; gA1 += 64; gB0 += 64; gB1 += 64;
    __syncthreads();  // compiler drains vmcnt(0) before s_barrier -> LDS ready
    bf16x8 af[4], bfr[4];
#pragma unroll
    for (int i = 0; i < 4; i++)
      af[i] = *(const bf16x8*)&As[(wm + i * 16 + ln) * BK + ko];
#pragma unroll
    for (int j = 0; j < 4; j++)
      bfr[j] = *(const bf16x8*)&Bs[(wn + j * 16 + ln) * BK + ko];
#pragma unroll
    for (int i = 0; i < 4; i++)
#pragma unroll
      for (int j = 0; j < 4; j++)
        acc[i][j] =
            __builtin_amdgcn_mfma_f32_16x16x32_bf16(af[i], bfr[j], acc[i][j], 0, 0, 0);
  }

  if (MODE == 0) {
#pragma unroll
    for (int i = 0; i < 4; i++) {
#pragma unroll
      for (int j = 0; j < 4; j++) {
        const int colg = tile_n + wn + j * 16 + ln;
        const float bv = bias[colg];
#pragma unroll
        for (int r = 0; r < 4; r++) {
          const int rowg = tile_m + wm + i * 16 + ((lane >> 4) << 2) + r;
          const float val = fmaxf(acc[i][j][r] + bv, 0.f);
          if constexpr (OUTK != 1) outb[(size_t)rowg * FDIM + colg] = f2bf(val);
          if constexpr (OUTK != 0) outf[(size_t)rowg * FDIM + colg] = val;
        }
      }
    }
  } else {
    const int b = tile_m >> 11;  // /SDIM
    float tcol[4], vcol[4];
#pragma unroll
    for (int j = 0; j < 4; j++) {
      const int colg = tile_n + wn + j * 16 + ln;
      tcol[j] = t1[b * FDIM + colg];
      vcol[j] = vvec[colg];
    }
#pragma unroll
    for (int i = 0; i < 4; i++) {
#pragma unroll
      for (int r = 0; r < 4; r++) {
        float s = 0.f;
#pragma unroll
        for (int j = 0; j < 4; j++) s += tanhf(acc[i][j][r] + tcol[j]) * vcol[j];
        s += __shfl_xor(s, 1);
        s += __shfl_xor(s, 2);
        s += __shfl_xor(s, 4);
        s += __shfl_xor(s, 8);
        if (ln == 0) {
          const int rowg = tile_m + wm + i * 16 + ((lane >> 4) << 2) + r;
          atomicAdd(&logit[rowg], s);
        }
      }
    }
  }
}

// ---------------------------------------------------------------------------
// FALLBACK GEMM (reg-staged, f32 or bf16 A). LDS rows padded to 56 bf16
// (112 B = 7*16 B aligned, 28-bank stride -> ~2-way, conflict-free-ish)
// to cut the 8.4M SQ_LDS_BANK_CONFLICT of the unpadded 64 B stride.
// ---------------------------------------------------------------------------
template <int MODE, bool AF32, bool OUTF32>
__global__ __launch_bounds__(256) void gemm_bt(
    const void* __restrict__ Agv, const bf16* __restrict__ Bg,
    const float* __restrict__ bias, void* __restrict__ outp,
    const float* __restrict__ t1, const float* __restrict__ vvec,
    float* __restrict__ logit) {
  constexpr int BK = 32, K = 1024, LDP = 56;
  __shared__ __align__(16) bf16 As[128 * LDP];
  __shared__ __align__(16) bf16 Bs[128 * LDP];

  const int tid = threadIdx.x;
  const int lane = tid & 63;
  const int wave = tid >> 6;
  const int wm = (wave & 1) * 64;
  const int wn = (wave >> 1) * 64;
  const int tile_m = blockIdx.x * 128;
  const int tile_n = blockIdx.y * 128;
  const int ln = lane & 15;
  const int ko = (lane >> 4) * 8;

  f32x4 acc[4][4] = {};

  const int arow = tid >> 2;        // 0..63
  const int acol = (tid & 3) * 8;   // 0,8,16,24
  const size_t aoff = (size_t)(tile_m + arow) * K + acol;
  const size_t aoff2 = aoff + (size_t)64 * K;
  const bf16* gB = Bg + (size_t)(tile_n + arow) * K + acol;
  const size_t rstep = (size_t)64 * K;
  bf16* lA = &As[arow * LDP + acol];
  bf16* lA2 = &As[(64 + arow) * LDP + acol];
  bf16* lB = &Bs[arow * LDP + acol];
  bf16* lB2 = &Bs[(64 + arow) * LDP + acol];

  for (int k0 = 0; k0 < K; k0 += BK) {
    bf16x8 va, va2;
    if constexpr (AF32) {
      const float* pa = (const float*)Agv + aoff + k0;
      const float* pa2 = (const float*)Agv + aoff2 + k0;
      const float4 x0 = *(const float4*)pa, x1 = *(const float4*)(pa + 4);
      const float4 y0 = *(const float4*)pa2, y1 = *(const float4*)(pa2 + 4);
      va[0] = (__bf16)x0.x; va[1] = (__bf16)x0.y; va[2] = (__bf16)x0.z; va[3] = (__bf16)x0.w;
      va[4] = (__bf16)x1.x; va[5] = (__bf16)x1.y; va[6] = (__bf16)x1.z; va[7] = (__bf16)x1.w;
      va2[0] = (__bf16)y0.x; va2[1] = (__bf16)y0.y; va2[2] = (__bf16)y0.z; va2[3] = (__bf16)y0.w;
      va2[4] = (__bf16)y1.x; va2[5] = (__bf16)y1.y; va2[6] = (__bf16)y1.z; va2[7] = (__bf16)y1.w;
    } else {
      va = *(const bf16x8*)((const bf16*)Agv + aoff + k0);
      va2 = *(const bf16x8*)((const bf16*)Agv + aoff2 + k0);
    }
    const bf16x8 vb = *(const bf16x8*)(gB + k0);
    const bf16x8 vb2 = *(const bf16x8*)(gB + k0 + rstep);
    __syncthreads();  // prev iteration's fragment reads complete
    *(bf16x8*)lA = va;
    *(bf16x8*)lA2 = va2;
    *(bf16x8*)lB = vb;
    *(bf16x8*)lB2 = vb2;
    __syncthreads();
    bf16x8 af[4], bfr[4];
#pragma unroll
    for (int i = 0; i < 4; i++)
      af[i] = *(const bf16x8*)&As[(wm + i * 16 + ln) * LDP + ko];
#pragma unroll
    for (int j = 0; j < 4; j++)
      bfr[j] = *(const bf16x8*)&Bs[(wn + j * 16 + ln) * LDP + ko];
#pragma unroll
    for (int i = 0; i < 4; i++)
#pragma unroll
      for (int j = 0; j < 4; j++)
        acc[i][j] =
            __builtin_amdgcn_mfma_f32_16x16x32_bf16(af[i], bfr[j], acc[i][j], 0, 0, 0);
  }

  if (MODE == 0) {
#pragma unroll
    for (int i = 0; i < 4; i++) {
#pragma unroll
      for (int j = 0; j < 4; j++) {
        const int colg = tile_n + wn + j * 16 + ln;
        const float bv = bias[colg];
#pragma unroll
        for (int r = 0; r < 4; r++) {
          const int rowg = tile_m + wm + i * 16 + ((lane >> 4) << 2) + r;
          const float val = fmaxf(acc[i][j][r] + bv, 0.f);
          if constexpr (OUTF32)
            ((float*)outp)[(size_t)rowg * FDIM + colg] = val;
          else
            ((bf16*)outp)[(size_t)rowg * FDIM + colg] = f2bf(val);
        }
      }
    }
  } else {
    const int b = tile_m >> 11;  // /SDIM
    float tcol[4], vcol[4];
#pragma unroll
    for (int j = 0; j < 4; j++) {
      const int colg = tile_n + wn + j * 16 + ln;
      tcol[j] = t1[b * FDIM + colg];
      vcol[j] = vvec[colg];
    }
#pragma unroll
    for (int i = 0; i < 4; i++) {
#pragma unroll
      for (int r = 0; r < 4; r++) {
        float s = 0.f;
#pragma unroll
        for (int j = 0; j < 4; j++) s += tanhf(acc[i][j][r] + tcol[j]) * vcol[j];
        s += __shfl_xor(s, 1);
        s += __shfl_xor(s, 2);
        s += __shfl_xor(s, 4);
        s += __shfl_xor(s, 8);
        if (ln == 0) {
          const int rowg = tile_m + wm + i * 16 + ((lane >> 4) << 2) + r;
          atomicAdd(&logit[rowg], s);
        }
      }
    }
  }
}

// dst[n*K + k] = bf16(src[k*N + n]); src f32 [K,N]
__global__ void transpose_cvt_k(const float* __restrict__ src, bf16* __restrict__ dst,
                                int K, int N) {
  __shared__ bf16 t[32][33];
  const int n0 = blockIdx.x * 32, k0 = blockIdx.y * 32;
  const int tx = threadIdx.x, ty = threadIdx.y;
  for (int i = 0; i < 32; i += 8)
    t[ty + i][tx] = f2bf(src[(size_t)(k0 + ty + i) * N + n0 + tx]);
  __syncthreads();
  for (int i = 0; i < 32; i += 8)
    dst[(size_t)(n0 + ty + i) * K + k0 + tx] = t[tx][ty + i];
}

// out[i] = bf16(in[i]), 8 elems/thread, vectorized (same RNE as staging cast)
__global__ void cvt_bf16_k(const float* __restrict__ in, bf16* __restrict__ out) {
  const size_t i = ((size_t)blockIdx.x * 256 + threadIdx.x) * 8;
  const float4 a = *(const float4*)(in + i);
  const float4 b = *(const float4*)(in + i + 4);
  bf16x8 o;
  o[0] = (__bf16)a.x; o[1] = (__bf16)a.y; o[2] = (__bf16)a.z; o[3] = (__bf16)a.w;
  o[4] = (__bf16)b.x; o[5] = (__bf16)b.y; o[6] = (__bf16)b.z; o[7] = (__bf16)b.w;
  *(bf16x8*)(out + i) = o;
}

__global__ void zerof_k(float* __restrict__ a, int n) {
  const int i = blockIdx.x * 256 + threadIdx.x;
  if (i < n) a[i] = 0.f;
}

__global__ void copyf_k(const float* __restrict__ in, float* __restrict__ out, int n) {
  const int i = blockIdx.x * 256 + threadIdx.x;
  if (i < n) out[i] = in[i];
}

// outf[b,f] += sum_{s in chunk} M[b*S+s, f] * w[b,s]   (atomic, outf pre-zeroed)
__global__ void colreduce_k(const bf16* __restrict__ M, const float* __restrict__ w,
                            float* __restrict__ outf) {
  const int b = blockIdx.y;
  const int f = blockIdx.x * 256 + threadIdx.x;
  const int s0 = blockIdx.z * 128;
  const bf16* col = M + ((size_t)b * SDIM + s0) * FDIM + f;
  const float* wb = w + b * SDIM + s0;
  float acc = 0.f;
#pragma unroll 8
  for (int s = 0; s < 128; ++s) acc += bf2f(col[(size_t)s * FDIM]) * wb[s];
  atomicAdd(&outf[b * FDIM + f], acc);
}

// out[b,n] = sum_f invec[b,f] * w1[f,n] + bias[n]   (all f32)
__global__ void smallgemm_k(const float* __restrict__ invec, const float* __restrict__ w1,
                            const float* __restrict__ bias, float* __restrict__ out) {
  const int b = blockIdx.y;
  const int n = blockIdx.x * 256 + threadIdx.x;
  const float* q = invec + b * FDIM;
  float acc = 0.f;
#pragma unroll 8
  for (int f = 0; f < FDIM; ++f) acc += q[f] * w1[(size_t)f * FDIM + n];
  out[b * FDIM + n] = acc + bias[n];
}

__global__ void softmax_k(const float* __restrict__ logit, const float* __restrict__ mask,
                          float* __restrict__ alpha) {
  const int b = blockIdx.x, tid = threadIdx.x;
  __shared__ float red[4];
  float v[8];
  float lmax = -1e30f;
#pragma unroll
  for (int k = 0; k < 8; ++k) {
    const int s = tid + k * 256;
    const float m = (1.f - mask[b * SDIM + s]) * -10000.f;
    v[k] = logit[b * SDIM + s] + m;
    lmax = fmaxf(lmax, v[k]);
  }
  for (int m = 1; m < 64; m <<= 1) lmax = fmaxf(lmax, __shfl_xor(lmax, m));
  if ((tid & 63) == 0) red[tid >> 6] = lmax;
  __syncthreads();
  lmax = fmaxf(fmaxf(red[0], red[1]), fmaxf(red[2], red[3]));
  __syncthreads();
  float lsum = 0.f;
#pragma unroll
  for (int k = 0; k < 8; ++k) {
    v[k] = expf(v[k] - lmax);
    lsum += v[k];
  }
  for (int m = 1; m < 64; m <<= 1) lsum += __shfl_xor(lsum, m);
  if ((tid & 63) == 0) red[tid >> 6] = lsum;
  __syncthreads();
  const float inv = 1.f / (red[0] + red[1] + red[2] + red[3]);
#pragma unroll
  for (int k = 0; k < 8; ++k) alpha[b * SDIM + tid + k * 256] = v[k] * inv;
}

__global__ void sparsemax_k(const float* __restrict__ Ll, const float* __restrict__ mask,
                            const float* __restrict__ w1s, const float* __restrict__ w2s,
                            const float* __restrict__ w3s, const int* __restrict__ layer_i,
                            float* __restrict__ Lout) {
  const int b = blockIdx.x, tid = threadIdx.x;
  __shared__ float red[4];
  const float a1 = w1s[0], a2 = w2s[0], a3 = w3s[0];
  const int li = layer_i[0];
  const float x = (li == 0) ? (a3 * a3 - a2 * a2 - a1 * a1)
                            : ((li == 1) ? (a3 * a3 - a2 * a2) : (a3 * a3));
  const float sig = 1.f / (1.f + expf(-x));
  float z[8];
  float lmax = -1e30f;
#pragma unroll
  for (int k = 0; k < 8; ++k) {
    const int s = tid + k * 256;
    const float m = (1.f - mask[b * SDIM + s]) * -10000.f;
    z[k] = Ll[b * SDIM + s] * sig + m;
    lmax = fmaxf(lmax, z[k]);
  }
  for (int m = 1; m < 64; m <<= 1) lmax = fmaxf(lmax, __shfl_xor(lmax, m));
  if ((tid & 63) == 0) red[tid >> 6] = lmax;
  __syncthreads();
  const float zmax = fmaxf(fmaxf(red[0], red[1]), fmaxf(red[2], red[3]));
  __syncthreads();
  float lo = zmax - 1.f, hi = zmax;
  for (int it = 0; it < 40; ++it) {
    const float tau = 0.5f * (lo + hi);
    float ssum = 0.f;
#pragma unroll
    for (int k = 0; k < 8; ++k) ssum += fmaxf(z[k] - tau, 0.f);
    for (int m = 1; m < 64; m <<= 1) ssum += __shfl_xor(ssum, m);
    if ((tid & 63) == 0) red[tid >> 6] = ssum;
    __syncthreads();
    const float tot = red[0] + red[1] + red[2] + red[3];
    __syncthreads();
    if (tot > 1.f) lo = tau; else hi = tau;
  }
  const float tau = 0.5f * (lo + hi);
#pragma unroll
  for (int k = 0; k < 8; ++k)
    Lout[b * SDIM + tid + k * 256] = fmaxf(z[k] - tau, 0.f);
}

extern "C" void kernel_launch(void* const* d_in, const int* in_sizes, int n_in,
                              void* d_out, int out_size, void* d_ws, size_t ws_size,
                              hipStream_t stream) {
  const float* mask = (const float*)d_in[0];
  const float* xlnet = (const float*)d_in[1];
  const float* iw = (const float*)d_in[2];
  const float* W_C = (const float*)d_in[3];
  const float* b_C = (const float*)d_in[4];
  const float* W_A = (const float*)d_in[5];
  const float* b_A = (const float*)d_in[6];
  const float* w1 = (const float*)d_in[7];
  const float* w2 = (const float*)d_in[8];
  const float* attn_bias = (const float*)d_in[9];
  const float* v = (const float*)d_in[10];
  const float* w_1 = (const float*)d_in[11];
  const float* w_2 = (const float*)d_in[12];
  const float* w_3 = (const float*)d_in[13];
  const int* layer_i = (const int*)d_in[14];

  float* out = (float*)d_out;
  float* h_out = out;                 // 16384 f32
  float* L_out = out + 16384;         // 32768 f32
  float* A_out = out + 49152;         // 33554432 f32 (134 MB)
  bf16* Cbuf = (bf16*)A_out;          // C (bf16, 67 MB) staged in A's slot,
                                      // fully consumed before A overwrites it.

  // ws: 3 bf16 transposed weights (6 MB) + f32 smalls (~655 KB) [+ tiers].
  char* ws = (char*)d_ws;
  bf16* WT_C = (bf16*)(ws);                      // 2 MB
  bf16* WT_A = (bf16*)(ws + 2097152);            // 2 MB
  bf16* w2T = (bf16*)(ws + 4194304);             // 2 MB
  float* qbuf = (float*)(ws + 6291456);          // 64 KB
  float* t1q = (float*)(ws + 6356992);           // 64 KB
  float* t1h = (float*)(ws + 6422528);           // 64 KB
  float* hbuf = (float*)(ws + 6488064);          // 64 KB
  float* a_logit = (float*)(ws + 6553600);       // 128 KB
  float* alpha = (float*)(ws + 6684672);         // 128 KB
  float* L_logit = (float*)(ws + 6815744);       // 128 KB -> end 6946816
  // Tier buffers (only used if ws_size permits; otherwise full fallback):
  bf16* Xbf = (bf16*)(ws + 6946816);             // 67108864 B: bf16(X)
  bf16* Abf = (bf16*)(ws + 74055680);            // 67108864 B: bf16(A)
  const bool t1ok = ws_size >= (size_t)74055680;   // Xbf fits
  const bool t2ok = ws_size >= (size_t)141164544;  // Xbf + Abf fit

  const dim3 tb(32, 8);
  transpose_cvt_k<<<dim3(32, 32), tb, 0, stream>>>(W_C, WT_C, 1024, 1024);
  transpose_cvt_k<<<dim3(32, 32), tb, 0, stream>>>(W_A, WT_A, 1024, 1024);
  transpose_cvt_k<<<dim3(32, 32), tb, 0, stream>>>(w2, w2T, 1024, 1024);
  // zero qbuf..L_logit contiguous region (163840 floats)
  zerof_k<<<640, 256, 0, stream>>>(qbuf, 163840);

  const dim3 gg(BS / 128, FDIM / 128);

  if (t1ok)  // X -> bf16 once (RNE, identical to in-staging cast)
    cvt_bf16_k<<<16384, 256, 0, stream>>>(xlnet, Xbf);

  // C = relu(X@W_C + b_C) -> Cbuf (bf16, in A's output slot)
  if (t1ok)
    gemm_glds<0, 0><<<gg, 256, 0, stream>>>(Xbf, WT_C, b_C, Cbuf, nullptr,
                                            nullptr, nullptr, nullptr);
  else
    gemm_bt<0, true, false><<<gg, 256, 0, stream>>>(xlnet, WT_C, b_C, Cbuf,
                                                    nullptr, nullptr, nullptr);
  // q[b,f] = sum_s C * iw
  colreduce_k<<<dim3(4, BDIM, 16), 256, 0, stream>>>(Cbuf, iw, qbuf);
  // t1q = q @ w1 + attn_bias
  smallgemm_k<<<dim3(4, BDIM), 256, 0, stream>>>(qbuf, w1, attn_bias, t1q);
  // a_logit[m] = sum_n tanh((C@w2)[m,n] + t1q[b,n]) * v[n]
  if (t1ok)
    gemm_glds<1, 0><<<gg, 256, 0, stream>>>(Cbuf, w2T, nullptr, nullptr,
                                            nullptr, t1q, v, a_logit);
  else
    gemm_bt<1, false, false><<<gg, 256, 0, stream>>>(Cbuf, w2T, nullptr,
                                                     nullptr, t1q, v, a_logit);
  softmax_k<<<BDIM, 256, 0, stream>>>(a_logit, mask, alpha);
  // h[b,f] = sum_s C * alpha
  colreduce_k<<<dim3(4, BDIM, 16), 256, 0, stream>>>(Cbuf, alpha, hbuf);
  copyf_k<<<64, 256, 0, stream>>>(hbuf, h_out, BDIM * FDIM);
  smallgemm_k<<<dim3(4, BDIM), 256, 0, stream>>>(hbuf, w1, attn_bias, t1h);

  // A = relu(X@W_A + b_A) -> A_out f32 (overwrites Cbuf; C fully consumed).
  // Tier2 additionally emits Abf (bf16 copy, = what staging would produce).
  if (t2ok)
    gemm_glds<0, 2><<<gg, 256, 0, stream>>>(Xbf, WT_A, b_A, Abf, A_out,
                                            nullptr, nullptr, nullptr);
  else if (t1ok)
    gemm_glds<0, 1><<<gg, 256, 0, stream>>>(Xbf, WT_A, b_A, nullptr, A_out,
                                            nullptr, nullptr, nullptr);
  else
    gemm_bt<0, true, true><<<gg, 256, 0, stream>>>(xlnet, WT_A, b_A, A_out,
                                                   nullptr, nullptr, nullptr);
  // L_logit[m] = sum_n tanh((A@w2)[m,n] + t1h[b,n]) * v[n]
  if (t2ok)
    gemm_glds<1, 0><<<gg, 256, 0, stream>>>(Abf, w2T, nullptr, nullptr,
                                            nullptr, t1h, v, L_logit);
  else
    gemm_bt<1, true, false><<<gg, 256, 0, stream>>>(A_out, w2T, nullptr,
                                                    nullptr, t1h, v, L_logit);
  sparsemax_k<<<BDIM, 256, 0, stream>>>(L_logit, mask, w_1, w_2, w_3, layer_i, L_out);
}

// Round 3
// 802.301 us; speedup vs baseline: 1.1222x; 1.0327x over previous
//
#include <hip/hip_runtime.h>
#include <hip/hip_bf16.h>
#include <math.h>

typedef __hip_bfloat16 bf16;
typedef __bf16 bf16x8 __attribute__((ext_vector_type(8)));
typedef float f32x4 __attribute__((ext_vector_type(4)));

#define BDIM 16
#define SDIM 2048
#define FDIM 1024
#define BS (BDIM * SDIM)  // 32768

__device__ __forceinline__ float bf2f(bf16 x) { return __bfloat162float(x); }
__device__ __forceinline__ bf16 f2bf(float x) { return __float2bfloat16(x); }

// async global->LDS, 16B per lane. LDS dest is wave-uniform base + lane*16.
__device__ __forceinline__ void gload16(const void* g, void* l) {
  __builtin_amdgcn_global_load_lds(
      (const __attribute__((address_space(1))) unsigned int*)g,
      (__attribute__((address_space(3))) unsigned int*)l, 16, 0, 0);
}

// ---------------------------------------------------------------------------
// DUAL GEMM: 512 threads, 8 waves (2M x 4N of 64x32 sub-tiles), 128x128 tile,
// BK=32, glds staging of 3 tiles/iter, 2 accumulator sets (32 MFMA/iter/wave
// -> 2x work per barrier vs gemm_glds).
// MODE 0 (dual-B): S=X tile (A-op, rows bx*128), T0=WT_C, T1=WT_A (rows by*128)
//   out0b = bf16 relu(accC + b_C); out1f/out1b = f32/bf16 relu(accA + b_A)
// MODE 1 (dual-A): S=w2T tile (B-op, rows by*128), T0/T1 = A-op rows bx*256,
//   bx*256+128. Epilogue: logit[m] += sum_n tanh(acc+t1[b,n])*v[n] (atomic)
// ---------------------------------------------------------------------------
template <int MODE>
__global__ __launch_bounds__(512, 4) void gemm_dual(
    const bf16* __restrict__ Sg, const bf16* __restrict__ T0g,
    const bf16* __restrict__ T1g, const float* __restrict__ bias0,
    const float* __restrict__ bias1, bf16* __restrict__ out0b,
    bf16* __restrict__ out1b, float* __restrict__ out1f,
    const float* __restrict__ t1, const float* __restrict__ vvec,
    float* __restrict__ logit) {
  constexpr int BK = 32, K = 1024;
  __shared__ __align__(16) bf16 Ss[128 * BK];   // 8 KB
  __shared__ __align__(16) bf16 T0s[128 * BK];  // 8 KB
  __shared__ __align__(16) bf16 T1s[128 * BK];  // 8 KB

  const int tid = threadIdx.x;
  const int lane = tid & 63;
  const int wave = tid >> 6;            // 0..7
  const int wm = (wave & 1) * 64;
  const int wn = (wave >> 1) * 32;
  const int ln = lane & 15;
  const int ko = (lane >> 4) * 8;

  const int srow0 = (MODE == 0) ? blockIdx.x * 128 : blockIdx.y * 128;
  const int t0row0 = (MODE == 0) ? blockIdx.y * 128 : blockIdx.x * 256;
  const int t1row0 = t0row0 + ((MODE == 0) ? 0 : 128);

  f32x4 acc0[4][2] = {};
  f32x4 acc1[4][2] = {};

  // glds: 512 lanes x 16B = whole 8KB tile per call. wave w covers rows
  // w*16+(lane>>2), 16B col slot (lane&3).
  const int lrow = wave * 16 + (lane >> 2);
  const int lcolb = (lane & 3) * 16;
  const char* gS = (const char*)(Sg + (size_t)(srow0 + lrow) * K) + lcolb;
  const char* gT0 = (const char*)(T0g + (size_t)(t0row0 + lrow) * K) + lcolb;
  const char* gT1 = (const char*)(T1g + (size_t)(t1row0 + lrow) * K) + lcolb;
  char* lS = (char*)Ss + wave * 1024;
  char* lT0 = (char*)T0s + wave * 1024;
  char* lT1 = (char*)T1s + wave * 1024;

  for (int k0 = 0; k0 < K; k0 += BK) {
    __syncthreads();  // prev iteration's fragment reads complete
    gload16(gS, lS);
    gload16(gT0, lT0);
    gload16(gT1, lT1);
    gS += 64; gT0 += 64; gT1 += 64;
    __syncthreads();  // vmcnt(0) drained before barrier -> LDS ready
    if constexpr (MODE == 0) {
      bf16x8 av[4], b0[2], b1[2];
#pragma unroll
      for (int i = 0; i < 4; i++)
        av[i] = *(const bf16x8*)&Ss[(wm + i * 16 + ln) * BK + ko];
#pragma unroll
      for (int j = 0; j < 2; j++) {
        b0[j] = *(const bf16x8*)&T0s[(wn + j * 16 + ln) * BK + ko];
        b1[j] = *(const bf16x8*)&T1s[(wn + j * 16 + ln) * BK + ko];
      }
#pragma unroll
      for (int i = 0; i < 4; i++)
#pragma unroll
        for (int j = 0; j < 2; j++) {
          acc0[i][j] = __builtin_amdgcn_mfma_f32_16x16x32_bf16(av[i], b0[j], acc0[i][j], 0, 0, 0);
          acc1[i][j] = __builtin_amdgcn_mfma_f32_16x16x32_bf16(av[i], b1[j], acc1[i][j], 0, 0, 0);
        }
    } else {
      bf16x8 bv[2], a0[4], a1[4];
#pragma unroll
      for (int j = 0; j < 2; j++)
        bv[j] = *(const bf16x8*)&Ss[(wn + j * 16 + ln) * BK + ko];
#pragma unroll
      for (int i = 0; i < 4; i++) {
        a0[i] = *(const bf16x8*)&T0s[(wm + i * 16 + ln) * BK + ko];
        a1[i] = *(const bf16x8*)&T1s[(wm + i * 16 + ln) * BK + ko];
      }
#pragma unroll
      for (int i = 0; i < 4; i++)
#pragma unroll
        for (int j = 0; j < 2; j++) {
          acc0[i][j] = __builtin_amdgcn_mfma_f32_16x16x32_bf16(a0[i], bv[j], acc0[i][j], 0, 0, 0);
          acc1[i][j] = __builtin_amdgcn_mfma_f32_16x16x32_bf16(a1[i], bv[j], acc1[i][j], 0, 0, 0);
        }
    }
  }

  const int q4 = (lane >> 4) << 2;
  if constexpr (MODE == 0) {
#pragma unroll
    for (int i = 0; i < 4; i++) {
#pragma unroll
      for (int j = 0; j < 2; j++) {
        const int colg = blockIdx.y * 128 + wn + j * 16 + ln;
        const float bC = bias0[colg];
        const float bA = bias1[colg];
#pragma unroll
        for (int r = 0; r < 4; r++) {
          const int rowg = blockIdx.x * 128 + wm + i * 16 + q4 + r;
          const float c = fmaxf(acc0[i][j][r] + bC, 0.f);
          const float a = fmaxf(acc1[i][j][r] + bA, 0.f);
          out0b[(size_t)rowg * FDIM + colg] = f2bf(c);
          out1f[(size_t)rowg * FDIM + colg] = a;
          out1b[(size_t)rowg * FDIM + colg] = f2bf(a);
        }
      }
    }
  } else {
    const int b = t0row0 >> 11;  // both m-tiles in same batch (256 | 2048)
    float tcol[2], vcol[2];
#pragma unroll
    for (int j = 0; j < 2; j++) {
      const int colg = blockIdx.y * 128 + wn + j * 16 + ln;
      tcol[j] = t1[b * FDIM + colg];
      vcol[j] = vvec[colg];
    }
#pragma unroll
    for (int t = 0; t < 2; t++) {
#pragma unroll
      for (int i = 0; i < 4; i++) {
#pragma unroll
        for (int r = 0; r < 4; r++) {
          float s = 0.f;
#pragma unroll
          for (int j = 0; j < 2; j++)
            s += tanhf((t ? acc1[i][j][r] : acc0[i][j][r]) + tcol[j]) * vcol[j];
          s += __shfl_xor(s, 1);
          s += __shfl_xor(s, 2);
          s += __shfl_xor(s, 4);
          s += __shfl_xor(s, 8);
          if (ln == 0) {
            const int rowg = (t ? t1row0 : t0row0) + wm + i * 16 + q4 + r;
            atomicAdd(&logit[rowg], s);
          }
        }
      }
    }
  }
}

// ---------------------------------------------------------------------------
// Single-output glds GEMM (m97 structure) — used when tiers restrict.
// MODE 0: val = relu(acc + bias[n]) -> OUTK: 0=bf16 out, 1=f32 out, 2=both
// MODE 1: logit[m] += sum_n tanh(acc[m,n] + t1[b,n]) * v[n]   (atomicAdd)
// ---------------------------------------------------------------------------
template <int MODE, int OUTK>
__global__ __launch_bounds__(256) void gemm_glds(
    const bf16* __restrict__ Ag, const bf16* __restrict__ Bg,
    const float* __restrict__ bias, bf16* __restrict__ outb,
    float* __restrict__ outf, const float* __restrict__ t1,
    const float* __restrict__ vvec, float* __restrict__ logit) {
  constexpr int BK = 32, K = 1024;
  __shared__ __align__(16) bf16 As[128 * BK];
  __shared__ __align__(16) bf16 Bs[128 * BK];

  const int tid = threadIdx.x;
  const int lane = tid & 63;
  const int wave = tid >> 6;
  const int wm = (wave & 1) * 64;
  const int wn = (wave >> 1) * 64;
  const int tile_m = blockIdx.x * 128;
  const int tile_n = blockIdx.y * 128;
  const int ln = lane & 15;
  const int ko = (lane >> 4) * 8;

  f32x4 acc[4][4] = {};

  const int lrow = wave * 16 + (lane >> 2);
  const int lcolb = (lane & 3) * 16;
  const char* gA0 = (const char*)(Ag + (size_t)(tile_m + lrow) * K) + lcolb;
  const char* gA1 = (const char*)(Ag + (size_t)(tile_m + lrow + 64) * K) + lcolb;
  const char* gB0 = (const char*)(Bg + (size_t)(tile_n + lrow) * K) + lcolb;
  const char* gB1 = (const char*)(Bg + (size_t)(tile_n + lrow + 64) * K) + lcolb;
  char* lA0 = (char*)As + wave * 1024;
  char* lA1 = lA0 + 4096;
  char* lB0 = (char*)Bs + wave * 1024;
  char* lB1 = lB0 + 4096;

  for (int k0 = 0; k0 < K; k0 += BK) {
    __syncthreads();
    gload16(gA0, lA0);
    gload16(gA1, lA1);
    gload16(gB0, lB0);
    gload16(gB1, lB1);
    gA0 += 64; gA1 += 64; gB0 += 64; gB1 += 64;
    __syncthreads();
    bf16x8 af[4], bfr[4];
#pragma unroll
    for (int i = 0; i < 4; i++)
      af[i] = *(const bf16x8*)&As[(wm + i * 16 + ln) * BK + ko];
#pragma unroll
    for (int j = 0; j < 4; j++)
      bfr[j] = *(const bf16x8*)&Bs[(wn + j * 16 + ln) * BK + ko];
#pragma unroll
    for (int i = 0; i < 4; i++)
#pragma unroll
      for (int j = 0; j < 4; j++)
        acc[i][j] =
            __builtin_amdgcn_mfma_f32_16x16x32_bf16(af[i], bfr[j], acc[i][j], 0, 0, 0);
  }

  if (MODE == 0) {
#pragma unroll
    for (int i = 0; i < 4; i++) {
#pragma unroll
      for (int j = 0; j < 4; j++) {
        const int colg = tile_n + wn + j * 16 + ln;
        const float bv = bias[colg];
#pragma unroll
        for (int r = 0; r < 4; r++) {
          const int rowg = tile_m + wm + i * 16 + ((lane >> 4) << 2) + r;
          const float val = fmaxf(acc[i][j][r] + bv, 0.f);
          if constexpr (OUTK != 1) outb[(size_t)rowg * FDIM + colg] = f2bf(val);
          if constexpr (OUTK != 0) outf[(size_t)rowg * FDIM + colg] = val;
        }
      }
    }
  } else {
    const int b = tile_m >> 11;
    float tcol[4], vcol[4];
#pragma unroll
    for (int j = 0; j < 4; j++) {
      const int colg = tile_n + wn + j * 16 + ln;
      tcol[j] = t1[b * FDIM + colg];
      vcol[j] = vvec[colg];
    }
#pragma unroll
    for (int i = 0; i < 4; i++) {
#pragma unroll
      for (int r = 0; r < 4; r++) {
        float s = 0.f;
#pragma unroll
        for (int j = 0; j < 4; j++) s += tanhf(acc[i][j][r] + tcol[j]) * vcol[j];
        s += __shfl_xor(s, 1);
        s += __shfl_xor(s, 2);
        s += __shfl_xor(s, 4);
        s += __shfl_xor(s, 8);
        if (ln == 0) {
          const int rowg = tile_m + wm + i * 16 + ((lane >> 4) << 2) + r;
          atomicAdd(&logit[rowg], s);
        }
      }
    }
  }
}

// ---------------------------------------------------------------------------
// FALLBACK GEMM (reg-staged, f32 or bf16 A), tier-0/1 paths only.
// ---------------------------------------------------------------------------
template <int MODE, bool AF32, bool OUTF32>
__global__ __launch_bounds__(256) void gemm_bt(
    const void* __restrict__ Agv, const bf16* __restrict__ Bg,
    const float* __restrict__ bias, void* __restrict__ outp,
    const float* __restrict__ t1, const float* __restrict__ vvec,
    float* __restrict__ logit) {
  constexpr int BK = 32, K = 1024, LDP = 56;
  __shared__ __align__(16) bf16 As[128 * LDP];
  __shared__ __align__(16) bf16 Bs[128 * LDP];

  const int tid = threadIdx.x;
  const int lane = tid & 63;
  const int wave = tid >> 6;
  const int wm = (wave & 1) * 64;
  const int wn = (wave >> 1) * 64;
  const int tile_m = blockIdx.x * 128;
  const int tile_n = blockIdx.y * 128;
  const int ln = lane & 15;
  const int ko = (lane >> 4) * 8;

  f32x4 acc[4][4] = {};

  const int arow = tid >> 2;
  const int acol = (tid & 3) * 8;
  const size_t aoff = (size_t)(tile_m + arow) * K + acol;
  const size_t aoff2 = aoff + (size_t)64 * K;
  const bf16* gB = Bg + (size_t)(tile_n + arow) * K + acol;
  const size_t rstep = (size_t)64 * K;
  bf16* lA = &As[arow * LDP + acol];
  bf16* lA2 = &As[(64 + arow) * LDP + acol];
  bf16* lB = &Bs[arow * LDP + acol];
  bf16* lB2 = &Bs[(64 + arow) * LDP + acol];

  for (int k0 = 0; k0 < K; k0 += BK) {
    bf16x8 va, va2;
    if constexpr (AF32) {
      const float* pa = (const float*)Agv + aoff + k0;
      const float* pa2 = (const float*)Agv + aoff2 + k0;
      const float4 x0 = *(const float4*)pa, x1 = *(const float4*)(pa + 4);
      const float4 y0 = *(const float4*)pa2, y1 = *(const float4*)(pa2 + 4);
      va[0] = (__bf16)x0.x; va[1] = (__bf16)x0.y; va[2] = (__bf16)x0.z; va[3] = (__bf16)x0.w;
      va[4] = (__bf16)x1.x; va[5] = (__bf16)x1.y; va[6] = (__bf16)x1.z; va[7] = (__bf16)x1.w;
      va2[0] = (__bf16)y0.x; va2[1] = (__bf16)y0.y; va2[2] = (__bf16)y0.z; va2[3] = (__bf16)y0.w;
      va2[4] = (__bf16)y1.x; va2[5] = (__bf16)y1.y; va2[6] = (__bf16)y1.z; va2[7] = (__bf16)y1.w;
    } else {
      va = *(const bf16x8*)((const bf16*)Agv + aoff + k0);
      va2 = *(const bf16x8*)((const bf16*)Agv + aoff2 + k0);
    }
    const bf16x8 vb = *(const bf16x8*)(gB + k0);
    const bf16x8 vb2 = *(const bf16x8*)(gB + k0 + rstep);
    __syncthreads();
    *(bf16x8*)lA = va;
    *(bf16x8*)lA2 = va2;
    *(bf16x8*)lB = vb;
    *(bf16x8*)lB2 = vb2;
    __syncthreads();
    bf16x8 af[4], bfr[4];
#pragma unroll
    for (int i = 0; i < 4; i++)
      af[i] = *(const bf16x8*)&As[(wm + i * 16 + ln) * LDP + ko];
#pragma unroll
    for (int j = 0; j < 4; j++)
      bfr[j] = *(const bf16x8*)&Bs[(wn + j * 16 + ln) * LDP + ko];
#pragma unroll
    for (int i = 0; i < 4; i++)
#pragma unroll
      for (int j = 0; j < 4; j++)
        acc[i][j] =
            __builtin_amdgcn_mfma_f32_16x16x32_bf16(af[i], bfr[j], acc[i][j], 0, 0, 0);
  }

  if (MODE == 0) {
#pragma unroll
    for (int i = 0; i < 4; i++) {
#pragma unroll
      for (int j = 0; j < 4; j++) {
        const int colg = tile_n + wn + j * 16 + ln;
        const float bv = bias[colg];
#pragma unroll
        for (int r = 0; r < 4; r++) {
          const int rowg = tile_m + wm + i * 16 + ((lane >> 4) << 2) + r;
          const float val = fmaxf(acc[i][j][r] + bv, 0.f);
          if constexpr (OUTF32)
            ((float*)outp)[(size_t)rowg * FDIM + colg] = val;
          else
            ((bf16*)outp)[(size_t)rowg * FDIM + colg] = f2bf(val);
        }
      }
    }
  } else {
    const int b = tile_m >> 11;
    float tcol[4], vcol[4];
#pragma unroll
    for (int j = 0; j < 4; j++) {
      const int colg = tile_n + wn + j * 16 + ln;
      tcol[j] = t1[b * FDIM + colg];
      vcol[j] = vvec[colg];
    }
#pragma unroll
    for (int i = 0; i < 4; i++) {
#pragma unroll
      for (int r = 0; r < 4; r++) {
        float s = 0.f;
#pragma unroll
        for (int j = 0; j < 4; j++) s += tanhf(acc[i][j][r] + tcol[j]) * vcol[j];
        s += __shfl_xor(s, 1);
        s += __shfl_xor(s, 2);
        s += __shfl_xor(s, 4);
        s += __shfl_xor(s, 8);
        if (ln == 0) {
          const int rowg = tile_m + wm + i * 16 + ((lane >> 4) << 2) + r;
          atomicAdd(&logit[rowg], s);
        }
      }
    }
  }
}

// 3 weight transposes in one launch: dst[n*K+k] = bf16(src[k*N+n]), 1024x1024
__global__ void transpose_cvt3_k(const float* __restrict__ s0, const float* __restrict__ s1,
                                 const float* __restrict__ s2, bf16* __restrict__ d0,
                                 bf16* __restrict__ d1, bf16* __restrict__ d2) {
  __shared__ bf16 t[32][33];
  const float* src = (blockIdx.z == 0) ? s0 : (blockIdx.z == 1) ? s1 : s2;
  bf16* dst = (blockIdx.z == 0) ? d0 : (blockIdx.z == 1) ? d1 : d2;
  const int n0 = blockIdx.x * 32, k0 = blockIdx.y * 32;
  const int tx = threadIdx.x, ty = threadIdx.y;
  for (int i = 0; i < 32; i += 8)
    t[ty + i][tx] = f2bf(src[(size_t)(k0 + ty + i) * 1024 + n0 + tx]);
  __syncthreads();
  for (int i = 0; i < 32; i += 8)
    dst[(size_t)(n0 + ty + i) * 1024 + k0 + tx] = t[tx][ty + i];
}

// out[i] = bf16(in[i]), 8 elems/thread, vectorized (same RNE as staging cast)
__global__ void cvt_bf16_k(const float* __restrict__ in, bf16* __restrict__ out) {
  const size_t i = ((size_t)blockIdx.x * 256 + threadIdx.x) * 8;
  const float4 a = *(const float4*)(in + i);
  const float4 b = *(const float4*)(in + i + 4);
  bf16x8 o;
  o[0] = (__bf16)a.x; o[1] = (__bf16)a.y; o[2] = (__bf16)a.z; o[3] = (__bf16)a.w;
  o[4] = (__bf16)b.x; o[5] = (__bf16)b.y; o[6] = (__bf16)b.z; o[7] = (__bf16)b.w;
  *(bf16x8*)(out + i) = o;
}

__global__ void zerof_k(float* __restrict__ a, int n) {
  const int i = blockIdx.x * 256 + threadIdx.x;
  if (i < n) a[i] = 0.f;
}

__global__ void copyf_k(const float* __restrict__ in, float* __restrict__ out, int n) {
  const int i = blockIdx.x * 256 + threadIdx.x;
  if (i < n) out[i] = in[i];
}

// outf[b,f] += sum_{s in chunk} M[b*S+s, f] * w[b,s]   (atomic, outf pre-zeroed)
__global__ void colreduce_k(const bf16* __restrict__ M, const float* __restrict__ w,
                            float* __restrict__ outf) {
  const int b = blockIdx.y;
  const int f = blockIdx.x * 256 + threadIdx.x;
  const int s0 = blockIdx.z * 128;
  const bf16* col = M + ((size_t)b * SDIM + s0) * FDIM + f;
  const float* wb = w + b * SDIM + s0;
  float acc = 0.f;
#pragma unroll 8
  for (int s = 0; s < 128; ++s) acc += bf2f(col[(size_t)s * FDIM]) * wb[s];
  atomicAdd(&outf[b * FDIM + f], acc);
}

// out[b,n] = sum_f invec[b,f] * w1[f,n] + bias[n]   (all f32)
__global__ void smallgemm_k(const float* __restrict__ invec, const float* __restrict__ w1,
                            const float* __restrict__ bias, float* __restrict__ out) {
  const int b = blockIdx.y;
  const int n = blockIdx.x * 256 + threadIdx.x;
  const float* q = invec + b * FDIM;
  float acc = 0.f;
#pragma unroll 8
  for (int f = 0; f < FDIM; ++f) acc += q[f] * w1[(size_t)f * FDIM + n];
  out[b * FDIM + n] = acc + bias[n];
}

__global__ void softmax_k(const float* __restrict__ logit, const float* __restrict__ mask,
                          float* __restrict__ alpha) {
  const int b = blockIdx.x, tid = threadIdx.x;
  __shared__ float red[4];
  float v[8];
  float lmax = -1e30f;
#pragma unroll
  for (int k = 0; k < 8; ++k) {
    const int s = tid + k * 256;
    const float m = (1.f - mask[b * SDIM + s]) * -10000.f;
    v[k] = logit[b * SDIM + s] + m;
    lmax = fmaxf(lmax, v[k]);
  }
  for (int m = 1; m < 64; m <<= 1) lmax = fmaxf(lmax, __shfl_xor(lmax, m));
  if ((tid & 63) == 0) red[tid >> 6] = lmax;
  __syncthreads();
  lmax = fmaxf(fmaxf(red[0], red[1]), fmaxf(red[2], red[3]));
  __syncthreads();
  float lsum = 0.f;
#pragma unroll
  for (int k = 0; k < 8; ++k) {
    v[k] = expf(v[k] - lmax);
    lsum += v[k];
  }
  for (int m = 1; m < 64; m <<= 1) lsum += __shfl_xor(lsum, m);
  if ((tid & 63) == 0) red[tid >> 6] = lsum;
  __syncthreads();
  const float inv = 1.f / (red[0] + red[1] + red[2] + red[3]);
#pragma unroll
  for (int k = 0; k < 8; ++k) alpha[b * SDIM + tid + k * 256] = v[k] * inv;
}

__global__ void sparsemax_k(const float* __restrict__ Ll, const float* __restrict__ mask,
                            const float* __restrict__ w1s, const float* __restrict__ w2s,
                            const float* __restrict__ w3s, const int* __restrict__ layer_i,
                            float* __restrict__ Lout) {
  const int b = blockIdx.x, tid = threadIdx.x;
  __shared__ float red[4];
  const float a1 = w1s[0], a2 = w2s[0], a3 = w3s[0];
  const int li = layer_i[0];
  const float x = (li == 0) ? (a3 * a3 - a2 * a2 - a1 * a1)
                            : ((li == 1) ? (a3 * a3 - a2 * a2) : (a3 * a3));
  const float sig = 1.f / (1.f + expf(-x));
  float z[8];
  float lmax = -1e30f;
#pragma unroll
  for (int k = 0; k < 8; ++k) {
    const int s = tid + k * 256;
    const float m = (1.f - mask[b * SDIM + s]) * -10000.f;
    z[k] = Ll[b * SDIM + s] * sig + m;
    lmax = fmaxf(lmax, z[k]);
  }
  for (int m = 1; m < 64; m <<= 1) lmax = fmaxf(lmax, __shfl_xor(lmax, m));
  if ((tid & 63) == 0) red[tid >> 6] = lmax;
  __syncthreads();
  const float zmax = fmaxf(fmaxf(red[0], red[1]), fmaxf(red[2], red[3]));
  __syncthreads();
  float lo = zmax - 1.f, hi = zmax;
  for (int it = 0; it < 40; ++it) {
    const float tau = 0.5f * (lo + hi);
    float ssum = 0.f;
#pragma unroll
    for (int k = 0; k < 8; ++k) ssum += fmaxf(z[k] - tau, 0.f);
    for (int m = 1; m < 64; m <<= 1) ssum += __shfl_xor(ssum, m);
    if ((tid & 63) == 0) red[tid >> 6] = ssum;
    __syncthreads();
    const float tot = red[0] + red[1] + red[2] + red[3];
    __syncthreads();
    if (tot > 1.f) lo = tau; else hi = tau;
  }
  const float tau = 0.5f * (lo + hi);
#pragma unroll
  for (int k = 0; k < 8; ++k)
    Lout[b * SDIM + tid + k * 256] = fmaxf(z[k] - tau, 0.f);
}

extern "C" void kernel_launch(void* const* d_in, const int* in_sizes, int n_in,
                              void* d_out, int out_size, void* d_ws, size_t ws_size,
                              hipStream_t stream) {
  const float* mask = (const float*)d_in[0];
  const float* xlnet = (const float*)d_in[1];
  const float* iw = (const float*)d_in[2];
  const float* W_C = (const float*)d_in[3];
  const float* b_C = (const float*)d_in[4];
  const float* W_A = (const float*)d_in[5];
  const float* b_A = (const float*)d_in[6];
  const float* w1 = (const float*)d_in[7];
  const float* w2 = (const float*)d_in[8];
  const float* attn_bias = (const float*)d_in[9];
  const float* v = (const float*)d_in[10];
  const float* w_1 = (const float*)d_in[11];
  const float* w_2 = (const float*)d_in[12];
  const float* w_3 = (const float*)d_in[13];
  const int* layer_i = (const int*)d_in[14];

  float* out = (float*)d_out;
  float* h_out = out;                 // 16384 f32
  float* L_out = out + 16384;         // 32768 f32
  float* A_out = out + 49152;         // 33554432 f32 (134 MB)

  // ws layout: bf16 weights (6 MB) + f32 smalls (~655 KB) + tier buffers.
  char* ws = (char*)d_ws;
  bf16* WT_C = (bf16*)(ws);                      // 2 MB
  bf16* WT_A = (bf16*)(ws + 2097152);            // 2 MB
  bf16* w2T = (bf16*)(ws + 4194304);             // 2 MB
  float* qbuf = (float*)(ws + 6291456);          // 64 KB
  float* t1q = (float*)(ws + 6356992);           // 64 KB
  float* t1h = (float*)(ws + 6422528);           // 64 KB
  float* hbuf = (float*)(ws + 6488064);          // 64 KB
  float* a_logit = (float*)(ws + 6553600);       // 128 KB
  float* alpha = (float*)(ws + 6684672);         // 128 KB
  float* L_logit = (float*)(ws + 6815744);       // 128 KB -> end 6946816
  bf16* Xbf = (bf16*)(ws + 6946816);             // 64 MB: bf16(X)
  bf16* Abf = (bf16*)(ws + 74055680);            // 64 MB: bf16(A)
  bf16* Cws = (bf16*)(ws + 141164544);           // 64 MB: bf16(C), tier 3
  const bool t1ok = ws_size >= (size_t)74055680;   // Xbf fits
  const bool t2ok = ws_size >= (size_t)141164544;  // + Abf
  const bool t3ok = ws_size >= (size_t)208273408;  // + Cws (C&A fusion)

  // Cbuf: tier3 -> own ws slot (C&A computed together); else staged in A_out.
  bf16* Cbuf = t3ok ? Cws : (bf16*)A_out;

  const dim3 tb(32, 8);
  transpose_cvt3_k<<<dim3(32, 32, 3), tb, 0, stream>>>(W_C, W_A, w2, WT_C, WT_A, w2T);
  zerof_k<<<640, 256, 0, stream>>>(qbuf, 163840);  // qbuf..L_logit contiguous

  const dim3 gg(BS / 128, FDIM / 128);     // 256 x 8
  const dim3 gd(BS / 256, FDIM / 128);     // 128 x 8 (dual-m MODE1)

  if (t1ok)  // X -> bf16 once (RNE, identical to in-staging cast)
    cvt_bf16_k<<<16384, 256, 0, stream>>>(xlnet, Xbf);

  // ---- C = relu(X@W_C + b_C)  [+ A fused at tier 3] ----
  if (t3ok)
    gemm_dual<0><<<gg, 512, 0, stream>>>(Xbf, WT_C, WT_A, b_C, b_A,
                                         Cbuf, Abf, A_out, nullptr, nullptr, nullptr);
  else if (t1ok)
    gemm_glds<0, 0><<<gg, 256, 0, stream>>>(Xbf, WT_C, b_C, Cbuf, nullptr,
                                            nullptr, nullptr, nullptr);
  else
    gemm_bt<0, true, false><<<gg, 256, 0, stream>>>(xlnet, WT_C, b_C, Cbuf,
                                                    nullptr, nullptr, nullptr);
  // q[b,f] = sum_s C * iw
  colreduce_k<<<dim3(4, BDIM, 16), 256, 0, stream>>>(Cbuf, iw, qbuf);
  // t1q = q @ w1 + attn_bias
  smallgemm_k<<<dim3(4, BDIM), 256, 0, stream>>>(qbuf, w1, attn_bias, t1q);
  // a_logit[m] = sum_n tanh((C@w2)[m,n] + t1q[b,n]) * v[n]  (dual-m, all tiers)
  gemm_dual<1><<<gd, 512, 0, stream>>>(w2T, Cbuf, Cbuf, nullptr, nullptr,
                                       nullptr, nullptr, nullptr, t1q, v, a_logit);
  softmax_k<<<BDIM, 256, 0, stream>>>(a_logit, mask, alpha);
  // h[b,f] = sum_s C * alpha
  colreduce_k<<<dim3(4, BDIM, 16), 256, 0, stream>>>(Cbuf, alpha, hbuf);
  copyf_k<<<64, 256, 0, stream>>>(hbuf, h_out, BDIM * FDIM);
  smallgemm_k<<<dim3(4, BDIM), 256, 0, stream>>>(hbuf, w1, attn_bias, t1h);

  // ---- A = relu(X@W_A + b_A) (if not already fused at tier 3) ----
  if (!t3ok) {
    if (t2ok)
      gemm_glds<0, 2><<<gg, 256, 0, stream>>>(Xbf, WT_A, b_A, Abf, A_out,
                                              nullptr, nullptr, nullptr);
    else if (t1ok)
      gemm_glds<0, 1><<<gg, 256, 0, stream>>>(Xbf, WT_A, b_A, nullptr, A_out,
                                              nullptr, nullptr, nullptr);
    else
      gemm_bt<0, true, true><<<gg, 256, 0, stream>>>(xlnet, WT_A, b_A, A_out,
                                                     nullptr, nullptr, nullptr);
  }
  // ---- L_logit[m] = sum_n tanh((A@w2)[m,n] + t1h[b,n]) * v[n] ----
  if (t2ok)
    gemm_dual<1><<<gd, 512, 0, stream>>>(w2T, Abf, Abf, nullptr, nullptr,
                                         nullptr, nullptr, nullptr, t1h, v, L_logit);
  else
    gemm_bt<1, true, false><<<gg, 256, 0, stream>>>(A_out, w2T, nullptr,
                                                    nullptr, t1h, v, L_logit);
  sparsemax_k<<<BDIM, 256, 0, stream>>>(L_logit, mask, w_1, w_2, w_3, layer_i, L_out);
}